// Round 8
// baseline (521.359 us; speedup 1.0000x reference)
//
#include <hip/hip_runtime.h>
#include <math.h>

#define B 4
#define C 64
#define L 4096
#define OUTC 64
#define SCALE 10.0f
#define THRESH 1e-3f

typedef float v4f __attribute__((ext_vector_type(4)));
typedef short bf16x8 __attribute__((ext_vector_type(8)));
typedef unsigned short us8 __attribute__((ext_vector_type(8)));

__device__ __forceinline__ unsigned short f2bf(float x) {
    unsigned int u = __float_as_uint(x);
    u += 0x7fffu + ((u >> 16) & 1u);          // round-to-nearest-even
    return (unsigned short)(u >> 16);
}
__device__ __forceinline__ float bf2f(unsigned short h) {
    return __uint_as_float(((unsigned int)h) << 16);
}
__device__ __forceinline__ v4f mfma16(bf16x8 a, bf16x8 b, v4f c) {
    return __builtin_amdgcn_mfma_f32_16x16x32_bf16(a, b, c, 0, 0, 0);
}

// ---------------------------------------------------------------------------
// Projection: p = l2norm(W2 @ leaky(W1 @ x)) per column, emitted as bf16
// hi/lo planes in ROW-MAJOR [b*L + l][c] layout (c contiguous) so the scores
// kernel can load MFMA A/B fragments directly (8 contiguous c per lane).
// 512 blocks (2 inputs x 4 batches x 64 column-tiles) x 256 threads.
// ---------------------------------------------------------------------------
__global__ void __launch_bounds__(256) proj_kernel(
    const float* __restrict__ q_in, const float* __restrict__ k_in,
    const float* __restrict__ W1, const float* __restrict__ W2,
    unsigned short* __restrict__ Qh, unsigned short* __restrict__ Ql,
    unsigned short* __restrict__ Kh, unsigned short* __restrict__ Kl)
{
    int bid   = blockIdx.x;        // 0..511
    int which = bid >> 8;          // 0 = query, 1 = key
    int b     = (bid >> 6) & 3;
    int l0    = (bid & 63) << 6;
    int t     = threadIdx.x;
    int g     = t >> 6;            // 0..3
    int l     = t & 63;

    const float* __restrict__ src =
        (which ? k_in : q_in) + (size_t)b * C * L + l0 + l;
    unsigned short* __restrict__ dh = which ? Kh : Qh;
    unsigned short* __restrict__ dl = which ? Kl : Ql;

    __shared__ float Ht[128][65];   // [h][l], pad 65 -> conflict-free
    __shared__ float red[4][64];

    float xr[C];
    #pragma unroll
    for (int c = 0; c < C; ++c)
        xr[c] = src[(size_t)c * L];

    // Stage 1: H[o][l] for o in [g*32, g*32+32)
    #pragma unroll 1
    for (int oo = 0; oo < 32; oo += 4) {
        #pragma unroll
        for (int u = 0; u < 4; ++u) {
            int o = g * 32 + oo + u;
            float h0 = 0.f, h1 = 0.f, h2 = 0.f, h3 = 0.f;
            #pragma unroll
            for (int c = 0; c < C; c += 4) {
                h0 = fmaf(W1[o * C + c + 0], xr[c + 0], h0);
                h1 = fmaf(W1[o * C + c + 1], xr[c + 1], h1);
                h2 = fmaf(W1[o * C + c + 2], xr[c + 2], h2);
                h3 = fmaf(W1[o * C + c + 3], xr[c + 3], h3);
            }
            float h = (h0 + h1) + (h2 + h3);
            Ht[o][l] = (h >= 0.0f) ? h : 0.01f * h;   // LeakyReLU(0.01)
        }
    }
    __syncthreads();

    // Stage 2: Y[o][l] for o in [g*16, g*16+16)
    float y[16];
    #pragma unroll
    for (int u = 0; u < 16; ++u) y[u] = 0.f;

    #pragma unroll 1
    for (int hh = 0; hh < 2 * C; hh += 16) {
        float hr[16];
        #pragma unroll
        for (int r = 0; r < 16; ++r)
            hr[r] = Ht[hh + r][l];
        #pragma unroll
        for (int u = 0; u < 16; ++u) {
            int o = g * 16 + u;
            #pragma unroll
            for (int h = 0; h < 16; ++h)
                y[u] = fmaf(W2[o * (2 * C) + hh + h], hr[h], y[u]);
        }
    }

    // l2norm over all 64 output channels (cross-group via LDS)
    float ss = 0.f;
    #pragma unroll
    for (int u = 0; u < 16; ++u) ss = fmaf(y[u], y[u], ss);
    red[g][l] = ss;
    __syncthreads();
    float tot = red[0][l] + red[1][l] + red[2][l] + red[3][l];
    float inv = 1.0f / fmaxf(sqrtf(tot), 1e-12f);

    // Emit bf16 hi/lo split: val = hi + lo with |val-(hi+lo)| ~ 2^-18*|val|
    unsigned short hs[16], ls[16];
    #pragma unroll
    for (int u = 0; u < 16; ++u) {
        float val = y[u] * inv;
        hs[u] = f2bf(val);
        ls[u] = f2bf(val - bf2f(hs[u]));
    }
    size_t rowoff = ((size_t)b * L + l0 + l) * 64 + (size_t)g * 16;
    *(us8*)(dh + rowoff)     = *(us8*)&hs[0];
    *(us8*)(dh + rowoff + 8) = *(us8*)&hs[8];
    *(us8*)(dl + rowoff)     = *(us8*)&ls[0];
    *(us8*)(dl + rowoff + 8) = *(us8*)&ls[8];
}

// ---------------------------------------------------------------------------
// Scores via MFMA bf16x3 + softmax(fixed shift 10) + threshold.
// 512 blocks (b major) x 512 threads (8 waves); 32 q-rows per block.
// S = Qh*Kh + Qh*Kl + Ql*Kh (lo*lo dropped, ~4e-5 logit error). |S|<=10 so
// the softmax shift is the constant 10 (exp(S-10) in [2e-9,1], no max pass).
// Pass 1: waves own disjoint 512-col stripes, accumulate row sums (no
// prefetch registers -> low VGPR, no spill risk; no barriers).
// Pass 2: block-synchronous 128-col tiles. Each wave computes its 16-col
// sub-tile into an LDS transpose buffer; after a barrier all 512 threads
// store the 32x128 tile as FULL 128B-line contiguous rows (4 rows x 512 B
// per wave, nontemporal). This removes the 64 B partial-line scatter that
// caused TCC read-modify-write amplification (R4: WRITE_SIZE 422 MB for a
// 268 MB output).
// ---------------------------------------------------------------------------
__global__ void __launch_bounds__(512) scores_kernel(
    const unsigned short* __restrict__ Qh, const unsigned short* __restrict__ Ql,
    const unsigned short* __restrict__ Kh, const unsigned short* __restrict__ Kl,
    float* __restrict__ out)
{
    int bid  = blockIdx.x;          // 0..511
    int b    = bid >> 7;
    int r0   = (bid & 127) << 5;    // 32 rows
    int t    = threadIdx.x;
    int wave = t >> 6;
    int lane = t & 63;
    int quad = lane >> 4;
    int ln   = lane & 15;

    // A fragments: aQ[rt][c0][hi/lo], m = ln, k = quad*8 + j  (m120-verified)
    bf16x8 aQ[2][2][2];
    {
        size_t qbase = ((size_t)b * L + r0) * 64;
        #pragma unroll
        for (int rt = 0; rt < 2; ++rt) {
            size_t rowb = qbase + (size_t)(rt * 16 + ln) * 64 + quad * 8;
            #pragma unroll
            for (int c0 = 0; c0 < 2; ++c0) {
                aQ[rt][c0][0] = *(const bf16x8*)(Qh + rowb + c0 * 32);
                aQ[rt][c0][1] = *(const bf16x8*)(Ql + rowb + c0 * 32);
            }
        }
    }

    const size_t kbase = (size_t)b * L * 64;
    __shared__ float wsum[32][8];
    __shared__ float rinv[32];
    __shared__ float Pt[32][132];   // pass-2 transpose tile (pad -> no conflicts)

    // ---------------- pass 1: row sums of exp(S - 10) ----------------
    v4f ps[2];
    ps[0] = (v4f){0.f, 0.f, 0.f, 0.f};
    ps[1] = (v4f){0.f, 0.f, 0.f, 0.f};

    #pragma unroll 1
    for (int ct = 0; ct < 32; ++ct) {
        size_t kr = kbase + (size_t)(wave * 512 + ct * 16 + ln) * 64 + quad * 8;
        bf16x8 bh0 = *(const bf16x8*)(Kh + kr);
        bf16x8 bl0 = *(const bf16x8*)(Kl + kr);
        bf16x8 bh1 = *(const bf16x8*)(Kh + kr + 32);
        bf16x8 bl1 = *(const bf16x8*)(Kl + kr + 32);

        #pragma unroll
        for (int rt = 0; rt < 2; ++rt) {
            v4f acc = (v4f){0.f, 0.f, 0.f, 0.f};
            acc = mfma16(aQ[rt][0][0], bh0, acc);
            acc = mfma16(aQ[rt][0][1], bh0, acc);
            acc = mfma16(aQ[rt][0][0], bl0, acc);
            acc = mfma16(aQ[rt][1][0], bh1, acc);
            acc = mfma16(aQ[rt][1][1], bh1, acc);
            acc = mfma16(aQ[rt][1][0], bl1, acc);
            #pragma unroll
            for (int r = 0; r < 4; ++r)
                ps[rt][r] += __expf(fmaf(SCALE, acc[r], -SCALE));
        }
    }

    // reduce over the 16 ln-lanes (cols) per row, then across waves via LDS
    #pragma unroll
    for (int rt = 0; rt < 2; ++rt) {
        #pragma unroll
        for (int r = 0; r < 4; ++r) {
            float s = ps[rt][r];
            s += __shfl_xor(s, 1);
            s += __shfl_xor(s, 2);
            s += __shfl_xor(s, 4);
            s += __shfl_xor(s, 8);
            if (ln == 0) wsum[rt * 16 + quad * 4 + r][wave] = s;
        }
    }
    __syncthreads();
    if (t < 32) {
        float s = 0.f;
        #pragma unroll
        for (int w = 0; w < 8; ++w) s += wsum[t][w];
        rinv[t] = 1.0f / s;
    }
    __syncthreads();

    float rv[2][4];
    #pragma unroll
    for (int rt = 0; rt < 2; ++rt)
        #pragma unroll
        for (int r = 0; r < 4; ++r)
            rv[rt][r] = rinv[rt * 16 + quad * 4 + r];

    // ---------------- pass 2: recompute, normalize, threshold, store ------
    float* __restrict__ outb = out + ((size_t)b * L + r0) * L;
    int srow = t >> 4;            // 0..31  (cooperative store row)
    int scol = (t & 15) * 8;      // 0..120 (cooperative store col base)

    #pragma unroll 1
    for (int T = 0; T < 32; ++T) {
        int c0 = T * 128 + wave * 16;    // this wave's 16 cols of the tile
        size_t kr = kbase + (size_t)(c0 + ln) * 64 + quad * 8;
        bf16x8 bh0 = *(const bf16x8*)(Kh + kr);
        bf16x8 bl0 = *(const bf16x8*)(Kl + kr);
        bf16x8 bh1 = *(const bf16x8*)(Kh + kr + 32);
        bf16x8 bl1 = *(const bf16x8*)(Kl + kr + 32);

        #pragma unroll
        for (int rt = 0; rt < 2; ++rt) {
            v4f acc = (v4f){0.f, 0.f, 0.f, 0.f};
            acc = mfma16(aQ[rt][0][0], bh0, acc);
            acc = mfma16(aQ[rt][0][1], bh0, acc);
            acc = mfma16(aQ[rt][0][0], bl0, acc);
            acc = mfma16(aQ[rt][1][0], bh1, acc);
            acc = mfma16(aQ[rt][1][1], bh1, acc);
            acc = mfma16(aQ[rt][1][0], bl1, acc);
            #pragma unroll
            for (int r = 0; r < 4; ++r) {
                float w = __expf(fmaf(SCALE, acc[r], -SCALE)) * rv[rt][r];
                w = (w > THRESH) ? w : 0.f;
                // C/D layout: col = ln, row = quad*4 + r (m89/m91)
                Pt[rt * 16 + quad * 4 + r][wave * 16 + ln] = w;
            }
        }
        __syncthreads();

        // cooperative full-line store: 32 rows x 128 cols, 512 B/row
        v4f o0 = *(const v4f*)&Pt[srow][scol];
        v4f o1 = *(const v4f*)&Pt[srow][scol + 4];
        float* dst = outb + (size_t)srow * L + T * 128 + scol;
        __builtin_nontemporal_store(o0, (v4f*)dst);
        __builtin_nontemporal_store(o1, (v4f*)(dst + 4));
        __syncthreads();
    }
}

// ---------------------------------------------------------------------------
extern "C" void kernel_launch(void* const* d_in, const int* in_sizes, int n_in,
                              void* d_out, int out_size, void* d_ws, size_t ws_size,
                              hipStream_t stream) {
    const float* query = (const float*)d_in[0];
    const float* key   = (const float*)d_in[1];
    const float* W1    = (const float*)d_in[2];
    const float* W2    = (const float*)d_in[3];
    float* out = (float*)d_out;

    // ws layout (ushorts): Qh | Ql | Kh | Kl, each B*L*OUTC = 1048576 elems
    unsigned short* Qh = (unsigned short*)d_ws;
    unsigned short* Ql = Qh + (size_t)B * L * OUTC;
    unsigned short* Kh = Ql + (size_t)B * L * OUTC;
    unsigned short* Kl = Kh + (size_t)B * L * OUTC;

    hipLaunchKernelGGL(proj_kernel, dim3(512), dim3(256), 0, stream,
                       query, key, W1, W2, Qh, Ql, Kh, Kl);
    hipLaunchKernelGGL(scores_kernel, dim3(512), dim3(512), 0, stream,
                       Qh, Ql, Kh, Kl, out);
}

// Round 9
// 469.972 us; speedup vs baseline: 1.1093x; 1.1093x over previous
//
#include <hip/hip_runtime.h>
#include <math.h>

#define B 4
#define C 64
#define L 4096
#define OUTC 64
#define SCALE 10.0f
#define THRESH 1e-3f

typedef float v4f __attribute__((ext_vector_type(4)));
typedef short bf16x8 __attribute__((ext_vector_type(8)));
typedef unsigned short us8 __attribute__((ext_vector_type(8)));

__device__ __forceinline__ unsigned short f2bf(float x) {
    unsigned int u = __float_as_uint(x);
    u += 0x7fffu + ((u >> 16) & 1u);          // round-to-nearest-even
    return (unsigned short)(u >> 16);
}
__device__ __forceinline__ float bf2f(unsigned short h) {
    return __uint_as_float(((unsigned int)h) << 16);
}
__device__ __forceinline__ v4f mfma16(bf16x8 a, bf16x8 b, v4f c) {
    return __builtin_amdgcn_mfma_f32_16x16x32_bf16(a, b, c, 0, 0, 0);
}

// ---------------------------------------------------------------------------
// Projection: p = l2norm(W2 @ leaky(W1 @ x)) per column, emitted as bf16
// hi/lo planes in ROW-MAJOR [b*L + l][c] layout (c contiguous) so the scores
// kernels can load MFMA A/B fragments directly (8 contiguous c per lane).
// 512 blocks (2 inputs x 4 batches x 64 column-tiles) x 256 threads.
// ---------------------------------------------------------------------------
__global__ void __launch_bounds__(256) proj_kernel(
    const float* __restrict__ q_in, const float* __restrict__ k_in,
    const float* __restrict__ W1, const float* __restrict__ W2,
    unsigned short* __restrict__ Qh, unsigned short* __restrict__ Ql,
    unsigned short* __restrict__ Kh, unsigned short* __restrict__ Kl)
{
    int bid   = blockIdx.x;        // 0..511
    int which = bid >> 8;          // 0 = query, 1 = key
    int b     = (bid >> 6) & 3;
    int l0    = (bid & 63) << 6;
    int t     = threadIdx.x;
    int g     = t >> 6;            // 0..3
    int l     = t & 63;

    const float* __restrict__ src =
        (which ? k_in : q_in) + (size_t)b * C * L + l0 + l;
    unsigned short* __restrict__ dh = which ? Kh : Qh;
    unsigned short* __restrict__ dl = which ? Kl : Ql;

    __shared__ float Ht[128][65];   // [h][l], pad 65 -> conflict-free
    __shared__ float red[4][64];

    float xr[C];
    #pragma unroll
    for (int c = 0; c < C; ++c)
        xr[c] = src[(size_t)c * L];

    // Stage 1: H[o][l] for o in [g*32, g*32+32)
    #pragma unroll 1
    for (int oo = 0; oo < 32; oo += 4) {
        #pragma unroll
        for (int u = 0; u < 4; ++u) {
            int o = g * 32 + oo + u;
            float h0 = 0.f, h1 = 0.f, h2 = 0.f, h3 = 0.f;
            #pragma unroll
            for (int c = 0; c < C; c += 4) {
                h0 = fmaf(W1[o * C + c + 0], xr[c + 0], h0);
                h1 = fmaf(W1[o * C + c + 1], xr[c + 1], h1);
                h2 = fmaf(W1[o * C + c + 2], xr[c + 2], h2);
                h3 = fmaf(W1[o * C + c + 3], xr[c + 3], h3);
            }
            float h = (h0 + h1) + (h2 + h3);
            Ht[o][l] = (h >= 0.0f) ? h : 0.01f * h;   // LeakyReLU(0.01)
        }
    }
    __syncthreads();

    // Stage 2: Y[o][l] for o in [g*16, g*16+16)
    float y[16];
    #pragma unroll
    for (int u = 0; u < 16; ++u) y[u] = 0.f;

    #pragma unroll 1
    for (int hh = 0; hh < 2 * C; hh += 16) {
        float hr[16];
        #pragma unroll
        for (int r = 0; r < 16; ++r)
            hr[r] = Ht[hh + r][l];
        #pragma unroll
        for (int u = 0; u < 16; ++u) {
            int o = g * 16 + u;
            #pragma unroll
            for (int h = 0; h < 16; ++h)
                y[u] = fmaf(W2[o * (2 * C) + hh + h], hr[h], y[u]);
        }
    }

    // l2norm over all 64 output channels (cross-group via LDS)
    float ss = 0.f;
    #pragma unroll
    for (int u = 0; u < 16; ++u) ss = fmaf(y[u], y[u], ss);
    red[g][l] = ss;
    __syncthreads();
    float tot = red[0][l] + red[1][l] + red[2][l] + red[3][l];
    float inv = 1.0f / fmaxf(sqrtf(tot), 1e-12f);

    // Emit bf16 hi/lo split: val = hi + lo with |val-(hi+lo)| ~ 2^-18*|val|
    unsigned short hs[16], ls[16];
    #pragma unroll
    for (int u = 0; u < 16; ++u) {
        float val = y[u] * inv;
        hs[u] = f2bf(val);
        ls[u] = f2bf(val - bf2f(hs[u]));
    }
    size_t rowoff = ((size_t)b * L + l0 + l) * 64 + (size_t)g * 16;
    *(us8*)(dh + rowoff)     = *(us8*)&hs[0];
    *(us8*)(dh + rowoff + 8) = *(us8*)&hs[8];
    *(us8*)(dl + rowoff)     = *(us8*)&ls[0];
    *(us8*)(dl + rowoff + 8) = *(us8*)&ls[8];
}

// ---------------------------------------------------------------------------
// Pass 1 kernel: row sums of exp(S - 10) -> rinv[b*L + row] = 1/sum.
// 512 blocks x 512 threads (8 waves, disjoint 512-col stripes, no barriers
// in the main loop). S = Qh*Kh + Qh*Kl + Ql*Kh. |S|<=10 (unit vectors x
// SCALE) so the softmax shift is the constant 10 -- no max pass needed.
// ---------------------------------------------------------------------------
__global__ void __launch_bounds__(512) sums_kernel(
    const unsigned short* __restrict__ Qh, const unsigned short* __restrict__ Ql,
    const unsigned short* __restrict__ Kh, const unsigned short* __restrict__ Kl,
    float* __restrict__ rinv_g)
{
    int bid  = blockIdx.x;          // 0..511
    int b    = bid >> 7;
    int r0   = (bid & 127) << 5;    // 32 rows
    int t    = threadIdx.x;
    int wave = t >> 6;
    int lane = t & 63;
    int quad = lane >> 4;
    int ln   = lane & 15;

    // A fragments: aQ[rt][c0][hi/lo], m = ln, k = quad*8 + j  (m120-verified)
    bf16x8 aQ[2][2][2];
    {
        size_t qbase = ((size_t)b * L + r0) * 64;
        #pragma unroll
        for (int rt = 0; rt < 2; ++rt) {
            size_t rowb = qbase + (size_t)(rt * 16 + ln) * 64 + quad * 8;
            #pragma unroll
            for (int c0 = 0; c0 < 2; ++c0) {
                aQ[rt][c0][0] = *(const bf16x8*)(Qh + rowb + c0 * 32);
                aQ[rt][c0][1] = *(const bf16x8*)(Ql + rowb + c0 * 32);
            }
        }
    }

    const size_t kbase = (size_t)b * L * 64;
    __shared__ float wsum[32][8];

    v4f ps[2];
    ps[0] = (v4f){0.f, 0.f, 0.f, 0.f};
    ps[1] = (v4f){0.f, 0.f, 0.f, 0.f};

    #pragma unroll 1
    for (int ct = 0; ct < 32; ++ct) {
        size_t kr = kbase + (size_t)(wave * 512 + ct * 16 + ln) * 64 + quad * 8;
        bf16x8 bh0 = *(const bf16x8*)(Kh + kr);
        bf16x8 bl0 = *(const bf16x8*)(Kl + kr);
        bf16x8 bh1 = *(const bf16x8*)(Kh + kr + 32);
        bf16x8 bl1 = *(const bf16x8*)(Kl + kr + 32);

        #pragma unroll
        for (int rt = 0; rt < 2; ++rt) {
            v4f acc = (v4f){0.f, 0.f, 0.f, 0.f};
            acc = mfma16(aQ[rt][0][0], bh0, acc);
            acc = mfma16(aQ[rt][0][1], bh0, acc);
            acc = mfma16(aQ[rt][0][0], bl0, acc);
            acc = mfma16(aQ[rt][1][0], bh1, acc);
            acc = mfma16(aQ[rt][1][1], bh1, acc);
            acc = mfma16(aQ[rt][1][0], bl1, acc);
            #pragma unroll
            for (int r = 0; r < 4; ++r)
                ps[rt][r] += __expf(fmaf(SCALE, acc[r], -SCALE));
        }
    }

    // reduce over the 16 ln-lanes (cols) per row, then across waves via LDS
    #pragma unroll
    for (int rt = 0; rt < 2; ++rt) {
        #pragma unroll
        for (int r = 0; r < 4; ++r) {
            float s = ps[rt][r];
            s += __shfl_xor(s, 1);
            s += __shfl_xor(s, 2);
            s += __shfl_xor(s, 4);
            s += __shfl_xor(s, 8);
            if (ln == 0) wsum[rt * 16 + quad * 4 + r][wave] = s;
        }
    }
    __syncthreads();
    if (t < 32) {
        float s = 0.f;
        #pragma unroll
        for (int w = 0; w < 8; ++w) s += wsum[t][w];
        rinv_g[(size_t)b * L + r0 + t] = 1.0f / s;
    }
}

// ---------------------------------------------------------------------------
// Pass 2 kernel: recompute S, w = exp(S-10)*rinv, threshold, store.
// 512 blocks x 512 threads. Block-cooperative 32x128 tiles with a
// DOUBLE-BUFFERED LDS transpose and ONE barrier per tile: compute tile T
// into buf[T&1]; barrier; all 512 threads store the tile as full 128-B
// lines (8 lanes cover one line in a single dwordx4 instruction), PLAIN
// stores (L2 write-back path -- the fill kernels prove this path runs at
// 6.3 TB/s). Stores issue at iteration end and retire during tile T+1's
// compute, so the next barrier's vmcnt drain is cheap. This replaces the
// scattered 64 B quad-stores (R4-R7: TCC partial-line RMW, WRITE_SIZE
// 432-488 MB for a 268 MB output) and R8's nt lockstep.
// ---------------------------------------------------------------------------
__global__ void __launch_bounds__(512) emit_kernel(
    const unsigned short* __restrict__ Qh, const unsigned short* __restrict__ Ql,
    const unsigned short* __restrict__ Kh, const unsigned short* __restrict__ Kl,
    const float* __restrict__ rinv_g, float* __restrict__ out)
{
    int bid  = blockIdx.x;          // 0..511
    int b    = bid >> 7;
    int r0   = (bid & 127) << 5;    // 32 rows
    int t    = threadIdx.x;
    int wave = t >> 6;
    int lane = t & 63;
    int quad = lane >> 4;
    int ln   = lane & 15;

    bf16x8 aQ[2][2][2];
    {
        size_t qbase = ((size_t)b * L + r0) * 64;
        #pragma unroll
        for (int rt = 0; rt < 2; ++rt) {
            size_t rowb = qbase + (size_t)(rt * 16 + ln) * 64 + quad * 8;
            #pragma unroll
            for (int c0 = 0; c0 < 2; ++c0) {
                aQ[rt][c0][0] = *(const bf16x8*)(Qh + rowb + c0 * 32);
                aQ[rt][c0][1] = *(const bf16x8*)(Ql + rowb + c0 * 32);
            }
        }
    }

    float rv[2][4];
    #pragma unroll
    for (int rt = 0; rt < 2; ++rt)
        #pragma unroll
        for (int r = 0; r < 4; ++r)
            rv[rt][r] = rinv_g[(size_t)b * L + r0 + rt * 16 + quad * 4 + r];

    const size_t kbase = (size_t)b * L * 64;
    __shared__ float Pt[2][32][132];   // double-buffered transpose tile

    float* __restrict__ outb = out + ((size_t)b * L + r0) * L;
    int srow = t >> 4;            // 0..31  (cooperative store row)
    int scol = (t & 15) * 8;      // 0..120 (cooperative store col base)

    #pragma unroll 1
    for (int T = 0; T < 32; ++T) {
        int buf = T & 1;
        int c0  = T * 128 + wave * 16;    // this wave's 16 cols of the tile
        size_t kr = kbase + (size_t)(c0 + ln) * 64 + quad * 8;
        bf16x8 bh0 = *(const bf16x8*)(Kh + kr);
        bf16x8 bl0 = *(const bf16x8*)(Kl + kr);
        bf16x8 bh1 = *(const bf16x8*)(Kh + kr + 32);
        bf16x8 bl1 = *(const bf16x8*)(Kl + kr + 32);

        #pragma unroll
        for (int rt = 0; rt < 2; ++rt) {
            v4f acc = (v4f){0.f, 0.f, 0.f, 0.f};
            acc = mfma16(aQ[rt][0][0], bh0, acc);
            acc = mfma16(aQ[rt][0][1], bh0, acc);
            acc = mfma16(aQ[rt][0][0], bl0, acc);
            acc = mfma16(aQ[rt][1][0], bh1, acc);
            acc = mfma16(aQ[rt][1][1], bh1, acc);
            acc = mfma16(aQ[rt][1][0], bl1, acc);
            #pragma unroll
            for (int r = 0; r < 4; ++r) {
                float w = __expf(fmaf(SCALE, acc[r], -SCALE)) * rv[rt][r];
                w = (w > THRESH) ? w : 0.f;
                // C/D layout: col = ln, row = quad*4 + r (m89/m91)
                Pt[buf][rt * 16 + quad * 4 + r][wave * 16 + ln] = w;
            }
        }
        __syncthreads();

        // cooperative full-line store: 32 rows x 128 cols, 512 B/row, plain
        v4f o0 = *(const v4f*)&Pt[buf][srow][scol];
        v4f o1 = *(const v4f*)&Pt[buf][srow][scol + 4];
        float* dst = outb + (size_t)srow * L + T * 128 + scol;
        *(v4f*)dst       = o0;
        *(v4f*)(dst + 4) = o1;
    }
}

// ---------------------------------------------------------------------------
extern "C" void kernel_launch(void* const* d_in, const int* in_sizes, int n_in,
                              void* d_out, int out_size, void* d_ws, size_t ws_size,
                              hipStream_t stream) {
    const float* query = (const float*)d_in[0];
    const float* key   = (const float*)d_in[1];
    const float* W1    = (const float*)d_in[2];
    const float* W2    = (const float*)d_in[3];
    float* out = (float*)d_out;

    // ws layout (ushorts): Qh | Ql | Kh | Kl, each B*L*OUTC = 1048576 elems;
    // then rinv (B*L floats)
    unsigned short* Qh = (unsigned short*)d_ws;
    unsigned short* Ql = Qh + (size_t)B * L * OUTC;
    unsigned short* Kh = Ql + (size_t)B * L * OUTC;
    unsigned short* Kl = Kh + (size_t)B * L * OUTC;
    float* rinv_g = (float*)(Kl + (size_t)B * L * OUTC);

    hipLaunchKernelGGL(proj_kernel, dim3(512), dim3(256), 0, stream,
                       query, key, W1, W2, Qh, Ql, Kh, Kl);
    hipLaunchKernelGGL(sums_kernel, dim3(512), dim3(512), 0, stream,
                       Qh, Ql, Kh, Kl, rinv_g);
    hipLaunchKernelGGL(emit_kernel, dim3(512), dim3(512), 0, stream,
                       Qh, Ql, Kh, Kl, rinv_g, out);
}

// Round 10
// 431.927 us; speedup vs baseline: 1.2071x; 1.0881x over previous
//
#include <hip/hip_runtime.h>
#include <math.h>

#define B 4
#define C 64
#define L 4096
#define OUTC 64
#define SCALE 10.0f
#define THRESH 1e-3f

typedef float v4f __attribute__((ext_vector_type(4)));
typedef short bf16x8 __attribute__((ext_vector_type(8)));
typedef unsigned short us8 __attribute__((ext_vector_type(8)));

__device__ __forceinline__ unsigned short f2bf(float x) {
    unsigned int u = __float_as_uint(x);
    u += 0x7fffu + ((u >> 16) & 1u);          // round-to-nearest-even
    return (unsigned short)(u >> 16);
}
__device__ __forceinline__ float bf2f(unsigned short h) {
    return __uint_as_float(((unsigned int)h) << 16);
}
__device__ __forceinline__ v4f mfma16(bf16x8 a, bf16x8 b, v4f c) {
    return __builtin_amdgcn_mfma_f32_16x16x32_bf16(a, b, c, 0, 0, 0);
}

// ---------------------------------------------------------------------------
// Projection: p = l2norm(W2 @ leaky(W1 @ x)) per column, emitted as bf16
// hi/lo planes in ROW-MAJOR [b*L + l][c] layout (c contiguous) so the scores
// kernels can load MFMA A/B fragments directly (8 contiguous c per lane).
// 512 blocks (2 inputs x 4 batches x 64 column-tiles) x 256 threads.
// ---------------------------------------------------------------------------
__global__ void __launch_bounds__(256) proj_kernel(
    const float* __restrict__ q_in, const float* __restrict__ k_in,
    const float* __restrict__ W1, const float* __restrict__ W2,
    unsigned short* __restrict__ Qh, unsigned short* __restrict__ Ql,
    unsigned short* __restrict__ Kh, unsigned short* __restrict__ Kl)
{
    int bid   = blockIdx.x;        // 0..511
    int which = bid >> 8;          // 0 = query, 1 = key
    int b     = (bid >> 6) & 3;
    int l0    = (bid & 63) << 6;
    int t     = threadIdx.x;
    int g     = t >> 6;            // 0..3
    int l     = t & 63;

    const float* __restrict__ src =
        (which ? k_in : q_in) + (size_t)b * C * L + l0 + l;
    unsigned short* __restrict__ dh = which ? Kh : Qh;
    unsigned short* __restrict__ dl = which ? Kl : Ql;

    __shared__ float Ht[128][65];   // [h][l], pad 65 -> conflict-free
    __shared__ float red[4][64];

    float xr[C];
    #pragma unroll
    for (int c = 0; c < C; ++c)
        xr[c] = src[(size_t)c * L];

    // Stage 1: H[o][l] for o in [g*32, g*32+32)
    #pragma unroll 1
    for (int oo = 0; oo < 32; oo += 4) {
        #pragma unroll
        for (int u = 0; u < 4; ++u) {
            int o = g * 32 + oo + u;
            float h0 = 0.f, h1 = 0.f, h2 = 0.f, h3 = 0.f;
            #pragma unroll
            for (int c = 0; c < C; c += 4) {
                h0 = fmaf(W1[o * C + c + 0], xr[c + 0], h0);
                h1 = fmaf(W1[o * C + c + 1], xr[c + 1], h1);
                h2 = fmaf(W1[o * C + c + 2], xr[c + 2], h2);
                h3 = fmaf(W1[o * C + c + 3], xr[c + 3], h3);
            }
            float h = (h0 + h1) + (h2 + h3);
            Ht[o][l] = (h >= 0.0f) ? h : 0.01f * h;   // LeakyReLU(0.01)
        }
    }
    __syncthreads();

    // Stage 2: Y[o][l] for o in [g*16, g*16+16)
    float y[16];
    #pragma unroll
    for (int u = 0; u < 16; ++u) y[u] = 0.f;

    #pragma unroll 1
    for (int hh = 0; hh < 2 * C; hh += 16) {
        float hr[16];
        #pragma unroll
        for (int r = 0; r < 16; ++r)
            hr[r] = Ht[hh + r][l];
        #pragma unroll
        for (int u = 0; u < 16; ++u) {
            int o = g * 16 + u;
            #pragma unroll
            for (int h = 0; h < 16; ++h)
                y[u] = fmaf(W2[o * (2 * C) + hh + h], hr[h], y[u]);
        }
    }

    // l2norm over all 64 output channels (cross-group via LDS)
    float ss = 0.f;
    #pragma unroll
    for (int u = 0; u < 16; ++u) ss = fmaf(y[u], y[u], ss);
    red[g][l] = ss;
    __syncthreads();
    float tot = red[0][l] + red[1][l] + red[2][l] + red[3][l];
    float inv = 1.0f / fmaxf(sqrtf(tot), 1e-12f);

    // Emit bf16 hi/lo split: val = hi + lo with |val-(hi+lo)| ~ 2^-18*|val|
    unsigned short hs[16], ls[16];
    #pragma unroll
    for (int u = 0; u < 16; ++u) {
        float val = y[u] * inv;
        hs[u] = f2bf(val);
        ls[u] = f2bf(val - bf2f(hs[u]));
    }
    size_t rowoff = ((size_t)b * L + l0 + l) * 64 + (size_t)g * 16;
    *(us8*)(dh + rowoff)     = *(us8*)&hs[0];
    *(us8*)(dh + rowoff + 8) = *(us8*)&hs[8];
    *(us8*)(dl + rowoff)     = *(us8*)&ls[0];
    *(us8*)(dl + rowoff + 8) = *(us8*)&ls[8];
}

// ---------------------------------------------------------------------------
// Pass 1 kernel: row sums of exp(S - 10) -> rinv[b*L + row] = 1/sum.
// 512 blocks x 512 threads (8 waves, disjoint 512-col stripes, no barriers
// in the main loop). S = Qh*Kh + Qh*Kl + Ql*Kh. |S|<=10 (unit vectors x
// SCALE) so the softmax shift is the constant 10 -- no max pass needed.
// ---------------------------------------------------------------------------
__global__ void __launch_bounds__(512) sums_kernel(
    const unsigned short* __restrict__ Qh, const unsigned short* __restrict__ Ql,
    const unsigned short* __restrict__ Kh, const unsigned short* __restrict__ Kl,
    float* __restrict__ rinv_g)
{
    int bid  = blockIdx.x;          // 0..511
    int b    = bid >> 7;
    int r0   = (bid & 127) << 5;    // 32 rows
    int t    = threadIdx.x;
    int wave = t >> 6;
    int lane = t & 63;
    int quad = lane >> 4;
    int ln   = lane & 15;

    // A fragments: aQ[rt][c0][hi/lo], m = ln, k = quad*8 + j  (m120-verified)
    bf16x8 aQ[2][2][2];
    {
        size_t qbase = ((size_t)b * L + r0) * 64;
        #pragma unroll
        for (int rt = 0; rt < 2; ++rt) {
            size_t rowb = qbase + (size_t)(rt * 16 + ln) * 64 + quad * 8;
            #pragma unroll
            for (int c0 = 0; c0 < 2; ++c0) {
                aQ[rt][c0][0] = *(const bf16x8*)(Qh + rowb + c0 * 32);
                aQ[rt][c0][1] = *(const bf16x8*)(Ql + rowb + c0 * 32);
            }
        }
    }

    const size_t kbase = (size_t)b * L * 64;
    __shared__ float wsum[32][8];

    v4f ps[2];
    ps[0] = (v4f){0.f, 0.f, 0.f, 0.f};
    ps[1] = (v4f){0.f, 0.f, 0.f, 0.f};

    #pragma unroll 1
    for (int ct = 0; ct < 32; ++ct) {
        size_t kr = kbase + (size_t)(wave * 512 + ct * 16 + ln) * 64 + quad * 8;
        bf16x8 bh0 = *(const bf16x8*)(Kh + kr);
        bf16x8 bl0 = *(const bf16x8*)(Kl + kr);
        bf16x8 bh1 = *(const bf16x8*)(Kh + kr + 32);
        bf16x8 bl1 = *(const bf16x8*)(Kl + kr + 32);

        #pragma unroll
        for (int rt = 0; rt < 2; ++rt) {
            v4f acc = (v4f){0.f, 0.f, 0.f, 0.f};
            acc = mfma16(aQ[rt][0][0], bh0, acc);
            acc = mfma16(aQ[rt][0][1], bh0, acc);
            acc = mfma16(aQ[rt][0][0], bl0, acc);
            acc = mfma16(aQ[rt][1][0], bh1, acc);
            acc = mfma16(aQ[rt][1][1], bh1, acc);
            acc = mfma16(aQ[rt][1][0], bl1, acc);
            #pragma unroll
            for (int r = 0; r < 4; ++r)
                ps[rt][r] += __expf(fmaf(SCALE, acc[r], -SCALE));
        }
    }

    // reduce over the 16 ln-lanes (cols) per row, then across waves via LDS
    #pragma unroll
    for (int rt = 0; rt < 2; ++rt) {
        #pragma unroll
        for (int r = 0; r < 4; ++r) {
            float s = ps[rt][r];
            s += __shfl_xor(s, 1);
            s += __shfl_xor(s, 2);
            s += __shfl_xor(s, 4);
            s += __shfl_xor(s, 8);
            if (ln == 0) wsum[rt * 16 + quad * 4 + r][wave] = s;
        }
    }
    __syncthreads();
    if (t < 32) {
        float s = 0.f;
        #pragma unroll
        for (int w = 0; w < 8; ++w) s += wsum[t][w];
        rinv_g[(size_t)b * L + r0 + t] = 1.0f / s;
    }
}

// ---------------------------------------------------------------------------
// Pass 2 kernel: recompute S, w = exp(S-10)*rinv, threshold, store.
// 512 blocks x 512 threads, 32x128 tiles, double-buffered LDS transpose,
// ONE barrier per tile. STORE MAPPING IS INSTRUCTION-LEVEL CONTIGUOUS:
// row = j*16 + (t>>5), col = (t&31)*4 -- each global_store_dwordx4 has
// 64 consecutive lanes covering 1024 B (two full 512 B row-segments = 8
// whole 128 B lines), the same pattern the 6.3 TB/s fill kernels use.
// All previous rounds wrote 16-64 B fragments per instruction -> TCC
// partial-line RMW -> WRITE_SIZE 432-488 MB for a 268 MB output and an
// effective ~2 TB/s write ceiling. Plain stores (L2 write-back).
// ---------------------------------------------------------------------------
__global__ void __launch_bounds__(512) emit_kernel(
    const unsigned short* __restrict__ Qh, const unsigned short* __restrict__ Ql,
    const unsigned short* __restrict__ Kh, const unsigned short* __restrict__ Kl,
    const float* __restrict__ rinv_g, float* __restrict__ out)
{
    int bid  = blockIdx.x;          // 0..511
    int b    = bid >> 7;
    int r0   = (bid & 127) << 5;    // 32 rows
    int t    = threadIdx.x;
    int wave = t >> 6;
    int lane = t & 63;
    int quad = lane >> 4;
    int ln   = lane & 15;

    bf16x8 aQ[2][2][2];
    {
        size_t qbase = ((size_t)b * L + r0) * 64;
        #pragma unroll
        for (int rt = 0; rt < 2; ++rt) {
            size_t rowb = qbase + (size_t)(rt * 16 + ln) * 64 + quad * 8;
            #pragma unroll
            for (int c0 = 0; c0 < 2; ++c0) {
                aQ[rt][c0][0] = *(const bf16x8*)(Qh + rowb + c0 * 32);
                aQ[rt][c0][1] = *(const bf16x8*)(Ql + rowb + c0 * 32);
            }
        }
    }

    float rv[2][4];
    #pragma unroll
    for (int rt = 0; rt < 2; ++rt)
        #pragma unroll
        for (int r = 0; r < 4; ++r)
            rv[rt][r] = rinv_g[(size_t)b * L + r0 + rt * 16 + quad * 4 + r];

    const size_t kbase = (size_t)b * L * 64;
    __shared__ float Pt[2][32][132];   // double-buffered transpose tile

    float* __restrict__ outb = out + ((size_t)b * L + r0) * L;
    int srow = t >> 5;            // 0..15 (store row within half-tile)
    int scol = (t & 31) * 4;      // 0..124 (16 B-aligned col)

    #pragma unroll 1
    for (int T = 0; T < 32; ++T) {
        int buf = T & 1;
        int c0  = T * 128 + wave * 16;    // this wave's 16 cols of the tile
        size_t kr = kbase + (size_t)(c0 + ln) * 64 + quad * 8;
        bf16x8 bh0 = *(const bf16x8*)(Kh + kr);
        bf16x8 bl0 = *(const bf16x8*)(Kl + kr);
        bf16x8 bh1 = *(const bf16x8*)(Kh + kr + 32);
        bf16x8 bl1 = *(const bf16x8*)(Kl + kr + 32);

        #pragma unroll
        for (int rt = 0; rt < 2; ++rt) {
            v4f acc = (v4f){0.f, 0.f, 0.f, 0.f};
            acc = mfma16(aQ[rt][0][0], bh0, acc);
            acc = mfma16(aQ[rt][0][1], bh0, acc);
            acc = mfma16(aQ[rt][0][0], bl0, acc);
            acc = mfma16(aQ[rt][1][0], bh1, acc);
            acc = mfma16(aQ[rt][1][1], bh1, acc);
            acc = mfma16(aQ[rt][1][0], bl1, acc);
            #pragma unroll
            for (int r = 0; r < 4; ++r) {
                float w = __expf(fmaf(SCALE, acc[r], -SCALE)) * rv[rt][r];
                w = (w > THRESH) ? w : 0.f;
                // C/D layout: col = ln, row = quad*4 + r (m89/m91)
                Pt[buf][rt * 16 + quad * 4 + r][wave * 16 + ln] = w;
            }
        }
        __syncthreads();

        // instruction-level line-complete cooperative store:
        // round j: 512 threads cover rows [j*16, j*16+16) x 128 cols;
        // each instruction = 64 lanes x 16 B fully contiguous (1 KiB).
        #pragma unroll
        for (int j = 0; j < 2; ++j) {
            int row = j * 16 + srow;
            v4f o = *(const v4f*)&Pt[buf][row][scol];
            *(v4f*)(outb + (size_t)row * L + T * 128 + scol) = o;
        }
    }
}

// ---------------------------------------------------------------------------
extern "C" void kernel_launch(void* const* d_in, const int* in_sizes, int n_in,
                              void* d_out, int out_size, void* d_ws, size_t ws_size,
                              hipStream_t stream) {
    const float* query = (const float*)d_in[0];
    const float* key   = (const float*)d_in[1];
    const float* W1    = (const float*)d_in[2];
    const float* W2    = (const float*)d_in[3];
    float* out = (float*)d_out;

    // ws layout (ushorts): Qh | Ql | Kh | Kl, each B*L*OUTC = 1048576 elems;
    // then rinv (B*L floats)
    unsigned short* Qh = (unsigned short*)d_ws;
    unsigned short* Ql = Qh + (size_t)B * L * OUTC;
    unsigned short* Kh = Ql + (size_t)B * L * OUTC;
    unsigned short* Kl = Kh + (size_t)B * L * OUTC;
    float* rinv_g = (float*)(Kl + (size_t)B * L * OUTC);

    hipLaunchKernelGGL(proj_kernel, dim3(512), dim3(256), 0, stream,
                       query, key, W1, W2, Qh, Ql, Kh, Kl);
    hipLaunchKernelGGL(sums_kernel, dim3(512), dim3(512), 0, stream,
                       Qh, Ql, Kh, Kl, rinv_g);
    hipLaunchKernelGGL(emit_kernel, dim3(512), dim3(512), 0, stream,
                       Qh, Ql, Kh, Kl, rinv_g, out);
}

// Round 11
// 430.063 us; speedup vs baseline: 1.2123x; 1.0043x over previous
//
#include <hip/hip_runtime.h>
#include <math.h>

#define B 4
#define C 64
#define L 4096
#define OUTC 64
#define SCALE 10.0f
#define THRESH 1e-3f

typedef float v4f __attribute__((ext_vector_type(4)));
typedef short bf16x8 __attribute__((ext_vector_type(8)));
typedef unsigned short us8 __attribute__((ext_vector_type(8)));

__device__ __forceinline__ unsigned short f2bf(float x) {
    unsigned int u = __float_as_uint(x);
    u += 0x7fffu + ((u >> 16) & 1u);          // round-to-nearest-even
    return (unsigned short)(u >> 16);
}
__device__ __forceinline__ float bf2f(unsigned short h) {
    return __uint_as_float(((unsigned int)h) << 16);
}
__device__ __forceinline__ v4f mfma16(bf16x8 a, bf16x8 b, v4f c) {
    return __builtin_amdgcn_mfma_f32_16x16x32_bf16(a, b, c, 0, 0, 0);
}

// ---------------------------------------------------------------------------
// Projection: p = l2norm(W2 @ leaky(W1 @ x)) per column, emitted as bf16
// hi/lo planes in ROW-MAJOR [b*L + l][c] layout (c contiguous) so the scores
// kernel can load MFMA A/B fragments directly (8 contiguous c per lane).
// 512 blocks (2 inputs x 4 batches x 64 column-tiles) x 256 threads.
// ---------------------------------------------------------------------------
__global__ void __launch_bounds__(256) proj_kernel(
    const float* __restrict__ q_in, const float* __restrict__ k_in,
    const float* __restrict__ W1, const float* __restrict__ W2,
    unsigned short* __restrict__ Qh, unsigned short* __restrict__ Ql,
    unsigned short* __restrict__ Kh, unsigned short* __restrict__ Kl)
{
    int bid   = blockIdx.x;        // 0..511
    int which = bid >> 8;          // 0 = query, 1 = key
    int b     = (bid >> 6) & 3;
    int l0    = (bid & 63) << 6;
    int t     = threadIdx.x;
    int g     = t >> 6;            // 0..3
    int l     = t & 63;

    const float* __restrict__ src =
        (which ? k_in : q_in) + (size_t)b * C * L + l0 + l;
    unsigned short* __restrict__ dh = which ? Kh : Qh;
    unsigned short* __restrict__ dl = which ? Kl : Ql;

    __shared__ float Ht[128][65];   // [h][l], pad 65 -> conflict-free
    __shared__ float red[4][64];

    float xr[C];
    #pragma unroll
    for (int c = 0; c < C; ++c)
        xr[c] = src[(size_t)c * L];

    // Stage 1: H[o][l] for o in [g*32, g*32+32)
    #pragma unroll 1
    for (int oo = 0; oo < 32; oo += 4) {
        #pragma unroll
        for (int u = 0; u < 4; ++u) {
            int o = g * 32 + oo + u;
            float h0 = 0.f, h1 = 0.f, h2 = 0.f, h3 = 0.f;
            #pragma unroll
            for (int c = 0; c < C; c += 4) {
                h0 = fmaf(W1[o * C + c + 0], xr[c + 0], h0);
                h1 = fmaf(W1[o * C + c + 1], xr[c + 1], h1);
                h2 = fmaf(W1[o * C + c + 2], xr[c + 2], h2);
                h3 = fmaf(W1[o * C + c + 3], xr[c + 3], h3);
            }
            float h = (h0 + h1) + (h2 + h3);
            Ht[o][l] = (h >= 0.0f) ? h : 0.01f * h;   // LeakyReLU(0.01)
        }
    }
    __syncthreads();

    // Stage 2: Y[o][l] for o in [g*16, g*16+16)
    float y[16];
    #pragma unroll
    for (int u = 0; u < 16; ++u) y[u] = 0.f;

    #pragma unroll 1
    for (int hh = 0; hh < 2 * C; hh += 16) {
        float hr[16];
        #pragma unroll
        for (int r = 0; r < 16; ++r)
            hr[r] = Ht[hh + r][l];
        #pragma unroll
        for (int u = 0; u < 16; ++u) {
            int o = g * 16 + u;
            #pragma unroll
            for (int h = 0; h < 16; ++h)
                y[u] = fmaf(W2[o * (2 * C) + hh + h], hr[h], y[u]);
        }
    }

    // l2norm over all 64 output channels (cross-group via LDS)
    float ss = 0.f;
    #pragma unroll
    for (int u = 0; u < 16; ++u) ss = fmaf(y[u], y[u], ss);
    red[g][l] = ss;
    __syncthreads();
    float tot = red[0][l] + red[1][l] + red[2][l] + red[3][l];
    float inv = 1.0f / fmaxf(sqrtf(tot), 1e-12f);

    // Emit bf16 hi/lo split: val = hi + lo with |val-(hi+lo)| ~ 2^-18*|val|
    unsigned short hs[16], ls[16];
    #pragma unroll
    for (int u = 0; u < 16; ++u) {
        float val = y[u] * inv;
        hs[u] = f2bf(val);
        ls[u] = f2bf(val - bf2f(hs[u]));
    }
    size_t rowoff = ((size_t)b * L + l0 + l) * 64 + (size_t)g * 16;
    *(us8*)(dh + rowoff)     = *(us8*)&hs[0];
    *(us8*)(dh + rowoff + 8) = *(us8*)&hs[8];
    *(us8*)(dl + rowoff)     = *(us8*)&ls[0];
    *(us8*)(dl + rowoff + 8) = *(us8*)&ls[8];
}

// ---------------------------------------------------------------------------
// Merged scores kernel: MFMA bf16x3, softmax(fixed shift 10), threshold.
// 512 blocks (b major) x 512 threads (8 waves); 32 q-rows per block.
// S = Qh*Kh + Qh*Kl + Ql*Kh (lo*lo dropped, ~4e-5 logit error). |S|<=10 so
// the softmax shift is the constant 10 (exp(S-10) in [2e-9,1], no max pass).
//
// Pass 1 (in-kernel): waves own disjoint 512-col stripes, accumulate row
// sums, reduce to LDS rinv[32]. One aQ fragment load serves both passes;
// pass-2's K reads hit L2 warm from pass 1.
//
// Pass 2: 32x128 tiles, double-buffered LDS transpose, ONE barrier per
// tile, and the R10-verified INSTRUCTION-LEVEL CONTIGUOUS cooperative
// store: row = j*16 + (t>>5), col = (t&31)*4 -- each global_store_dwordx4
// covers 1 KiB with 64 consecutive lanes (8 whole 128 B lines), plain L2
// write-back. Scattered sub-line stores (R4-R9) caused TCC partial-line
// RMW: WRITE_SIZE 432-488 MB for a 268 MB output, ~2 TB/s ceiling.
// ---------------------------------------------------------------------------
__global__ void __launch_bounds__(512) scores_kernel(
    const unsigned short* __restrict__ Qh, const unsigned short* __restrict__ Ql,
    const unsigned short* __restrict__ Kh, const unsigned short* __restrict__ Kl,
    float* __restrict__ out)
{
    int bid  = blockIdx.x;          // 0..511
    int b    = bid >> 7;
    int r0   = (bid & 127) << 5;    // 32 rows
    int t    = threadIdx.x;
    int wave = t >> 6;
    int lane = t & 63;
    int quad = lane >> 4;
    int ln   = lane & 15;

    // A fragments: aQ[rt][c0][hi/lo], m = ln, k = quad*8 + j  (m120-verified)
    bf16x8 aQ[2][2][2];
    {
        size_t qbase = ((size_t)b * L + r0) * 64;
        #pragma unroll
        for (int rt = 0; rt < 2; ++rt) {
            size_t rowb = qbase + (size_t)(rt * 16 + ln) * 64 + quad * 8;
            #pragma unroll
            for (int c0 = 0; c0 < 2; ++c0) {
                aQ[rt][c0][0] = *(const bf16x8*)(Qh + rowb + c0 * 32);
                aQ[rt][c0][1] = *(const bf16x8*)(Ql + rowb + c0 * 32);
            }
        }
    }

    const size_t kbase = (size_t)b * L * 64;
    __shared__ float wsum[32][8];
    __shared__ float rinv[32];
    __shared__ float Pt[2][32][132];   // double-buffered transpose tile

    // ---------------- pass 1: row sums of exp(S - 10) ----------------
    v4f ps[2];
    ps[0] = (v4f){0.f, 0.f, 0.f, 0.f};
    ps[1] = (v4f){0.f, 0.f, 0.f, 0.f};

    #pragma unroll 1
    for (int ct = 0; ct < 32; ++ct) {
        size_t kr = kbase + (size_t)(wave * 512 + ct * 16 + ln) * 64 + quad * 8;
        bf16x8 bh0 = *(const bf16x8*)(Kh + kr);
        bf16x8 bl0 = *(const bf16x8*)(Kl + kr);
        bf16x8 bh1 = *(const bf16x8*)(Kh + kr + 32);
        bf16x8 bl1 = *(const bf16x8*)(Kl + kr + 32);

        #pragma unroll
        for (int rt = 0; rt < 2; ++rt) {
            v4f acc = (v4f){0.f, 0.f, 0.f, 0.f};
            acc = mfma16(aQ[rt][0][0], bh0, acc);
            acc = mfma16(aQ[rt][0][1], bh0, acc);
            acc = mfma16(aQ[rt][0][0], bl0, acc);
            acc = mfma16(aQ[rt][1][0], bh1, acc);
            acc = mfma16(aQ[rt][1][1], bh1, acc);
            acc = mfma16(aQ[rt][1][0], bl1, acc);
            #pragma unroll
            for (int r = 0; r < 4; ++r)
                ps[rt][r] += __expf(fmaf(SCALE, acc[r], -SCALE));
        }
    }

    // reduce over the 16 ln-lanes (cols) per row, then across waves via LDS
    #pragma unroll
    for (int rt = 0; rt < 2; ++rt) {
        #pragma unroll
        for (int r = 0; r < 4; ++r) {
            float s = ps[rt][r];
            s += __shfl_xor(s, 1);
            s += __shfl_xor(s, 2);
            s += __shfl_xor(s, 4);
            s += __shfl_xor(s, 8);
            if (ln == 0) wsum[rt * 16 + quad * 4 + r][wave] = s;
        }
    }
    __syncthreads();
    if (t < 32) {
        float s = 0.f;
        #pragma unroll
        for (int w = 0; w < 8; ++w) s += wsum[t][w];
        rinv[t] = 1.0f / s;
    }
    __syncthreads();

    float rv[2][4];
    #pragma unroll
    for (int rt = 0; rt < 2; ++rt)
        #pragma unroll
        for (int r = 0; r < 4; ++r)
            rv[rt][r] = rinv[rt * 16 + quad * 4 + r];

    // ---------------- pass 2: recompute, normalize, threshold, store ------
    float* __restrict__ outb = out + ((size_t)b * L + r0) * L;
    int srow = t >> 5;            // 0..15 (store row within half-tile)
    int scol = (t & 31) * 4;      // 0..124 (16 B-aligned col)

    #pragma unroll 1
    for (int T = 0; T < 32; ++T) {
        int buf = T & 1;
        int c0  = T * 128 + wave * 16;    // this wave's 16 cols of the tile
        size_t kr = kbase + (size_t)(c0 + ln) * 64 + quad * 8;
        bf16x8 bh0 = *(const bf16x8*)(Kh + kr);
        bf16x8 bl0 = *(const bf16x8*)(Kl + kr);
        bf16x8 bh1 = *(const bf16x8*)(Kh + kr + 32);
        bf16x8 bl1 = *(const bf16x8*)(Kl + kr + 32);

        #pragma unroll
        for (int rt = 0; rt < 2; ++rt) {
            v4f acc = (v4f){0.f, 0.f, 0.f, 0.f};
            acc = mfma16(aQ[rt][0][0], bh0, acc);
            acc = mfma16(aQ[rt][0][1], bh0, acc);
            acc = mfma16(aQ[rt][0][0], bl0, acc);
            acc = mfma16(aQ[rt][1][0], bh1, acc);
            acc = mfma16(aQ[rt][1][1], bh1, acc);
            acc = mfma16(aQ[rt][1][0], bl1, acc);
            #pragma unroll
            for (int r = 0; r < 4; ++r) {
                float w = __expf(fmaf(SCALE, acc[r], -SCALE)) * rv[rt][r];
                w = (w > THRESH) ? w : 0.f;
                // C/D layout: col = ln, row = quad*4 + r (m89/m91)
                Pt[buf][rt * 16 + quad * 4 + r][wave * 16 + ln] = w;
            }
        }
        __syncthreads();

        // instruction-level line-complete cooperative store:
        // round j: 512 threads cover rows [j*16, j*16+16) x 128 cols;
        // each instruction = 64 lanes x 16 B fully contiguous (1 KiB).
        #pragma unroll
        for (int j = 0; j < 2; ++j) {
            int row = j * 16 + srow;
            v4f o = *(const v4f*)&Pt[buf][row][scol];
            *(v4f*)(outb + (size_t)row * L + T * 128 + scol) = o;
        }
    }
}

// ---------------------------------------------------------------------------
extern "C" void kernel_launch(void* const* d_in, const int* in_sizes, int n_in,
                              void* d_out, int out_size, void* d_ws, size_t ws_size,
                              hipStream_t stream) {
    const float* query = (const float*)d_in[0];
    const float* key   = (const float*)d_in[1];
    const float* W1    = (const float*)d_in[2];
    const float* W2    = (const float*)d_in[3];
    float* out = (float*)d_out;

    // ws layout (ushorts): Qh | Ql | Kh | Kl, each B*L*OUTC = 1048576 elems
    unsigned short* Qh = (unsigned short*)d_ws;
    unsigned short* Ql = Qh + (size_t)B * L * OUTC;
    unsigned short* Kh = Ql + (size_t)B * L * OUTC;
    unsigned short* Kl = Kh + (size_t)B * L * OUTC;

    hipLaunchKernelGGL(proj_kernel, dim3(512), dim3(256), 0, stream,
                       query, key, W1, W2, Qh, Ql, Kh, Kl);
    hipLaunchKernelGGL(scores_kernel, dim3(512), dim3(512), 0, stream,
                       Qh, Ql, Kh, Kl, out);
}

// Round 12
// 376.934 us; speedup vs baseline: 1.3832x; 1.1410x over previous
//
#include <hip/hip_runtime.h>
#include <math.h>

#define B 4
#define C 64
#define L 4096
#define OUTC 64
#define SCALE 10.0f
#define THRESH 1e-3f

typedef float v4f __attribute__((ext_vector_type(4)));
typedef short bf16x8 __attribute__((ext_vector_type(8)));
typedef unsigned short us8 __attribute__((ext_vector_type(8)));

__device__ __forceinline__ unsigned short f2bf(float x) {
    unsigned int u = __float_as_uint(x);
    u += 0x7fffu + ((u >> 16) & 1u);          // round-to-nearest-even
    return (unsigned short)(u >> 16);
}
__device__ __forceinline__ float bf2f(unsigned short h) {
    return __uint_as_float(((unsigned int)h) << 16);
}
__device__ __forceinline__ v4f mfma16(bf16x8 a, bf16x8 b, v4f c) {
    return __builtin_amdgcn_mfma_f32_16x16x32_bf16(a, b, c, 0, 0, 0);
}

// ---------------------------------------------------------------------------
// FRAGMENT-TILED operand layout (ushort units):
//   T(b,tile,chunk,lane,j) = ((b*256 + tile)*2 + chunk)*512 + lane*8 + j
// tile = col/16, chunk = c/32, lane = ((c&31)>>3)*16 + (col&15), j = c&7.
// This is the exact per-lane MFMA consumption order: a fragment load in the
// scores kernel is base + lane*16B -> 64 consecutive lanes x 16 B = ONE
// fully-contiguous 1 KB transaction (the pattern the 6.3 TB/s fill kernels
// use). The previous row-major [col][c] layout made every fragment load
// take 64 B halves of 16 different 128 B lines (16-lane stride of 128 B),
// risking 2x L2 read traffic -- the suspected cause of the ~150 us scores
// plateau that survived occupancy/prefetch/swizzle/store fixes (R5-R11).
// ---------------------------------------------------------------------------

// ---------------------------------------------------------------------------
// Projection: p = l2norm(W2 @ leaky(W1 @ x)) per column, emitted as bf16
// hi/lo planes directly in the fragment-tiled layout above.
// 512 blocks (2 inputs x 4 batches x 64 column-tiles) x 256 threads.
// ---------------------------------------------------------------------------
__global__ void __launch_bounds__(256) proj_kernel(
    const float* __restrict__ q_in, const float* __restrict__ k_in,
    const float* __restrict__ W1, const float* __restrict__ W2,
    unsigned short* __restrict__ Qh, unsigned short* __restrict__ Ql,
    unsigned short* __restrict__ Kh, unsigned short* __restrict__ Kl)
{
    int bid   = blockIdx.x;        // 0..511
    int which = bid >> 8;          // 0 = query, 1 = key
    int b     = (bid >> 6) & 3;
    int l0    = (bid & 63) << 6;
    int t     = threadIdx.x;
    int g     = t >> 6;            // 0..3  (owns channels [g*16, g*16+16))
    int l     = t & 63;

    const float* __restrict__ src =
        (which ? k_in : q_in) + (size_t)b * C * L + l0 + l;
    unsigned short* __restrict__ dh = which ? Kh : Qh;
    unsigned short* __restrict__ dl = which ? Kl : Ql;

    __shared__ float Ht[128][65];   // [h][l], pad 65 -> conflict-free
    __shared__ float red[4][64];

    float xr[C];
    #pragma unroll
    for (int c = 0; c < C; ++c)
        xr[c] = src[(size_t)c * L];

    // Stage 1: H[o][l] for o in [g*32, g*32+32)
    #pragma unroll 1
    for (int oo = 0; oo < 32; oo += 4) {
        #pragma unroll
        for (int u = 0; u < 4; ++u) {
            int o = g * 32 + oo + u;
            float h0 = 0.f, h1 = 0.f, h2 = 0.f, h3 = 0.f;
            #pragma unroll
            for (int c = 0; c < C; c += 4) {
                h0 = fmaf(W1[o * C + c + 0], xr[c + 0], h0);
                h1 = fmaf(W1[o * C + c + 1], xr[c + 1], h1);
                h2 = fmaf(W1[o * C + c + 2], xr[c + 2], h2);
                h3 = fmaf(W1[o * C + c + 3], xr[c + 3], h3);
            }
            float h = (h0 + h1) + (h2 + h3);
            Ht[o][l] = (h >= 0.0f) ? h : 0.01f * h;   // LeakyReLU(0.01)
        }
    }
    __syncthreads();

    // Stage 2: Y[o][l] for o in [g*16, g*16+16)
    float y[16];
    #pragma unroll
    for (int u = 0; u < 16; ++u) y[u] = 0.f;

    #pragma unroll 1
    for (int hh = 0; hh < 2 * C; hh += 16) {
        float hr[16];
        #pragma unroll
        for (int r = 0; r < 16; ++r)
            hr[r] = Ht[hh + r][l];
        #pragma unroll
        for (int u = 0; u < 16; ++u) {
            int o = g * 16 + u;
            #pragma unroll
            for (int h = 0; h < 16; ++h)
                y[u] = fmaf(W2[o * (2 * C) + hh + h], hr[h], y[u]);
        }
    }

    // l2norm over all 64 output channels (cross-group via LDS)
    float ss = 0.f;
    #pragma unroll
    for (int u = 0; u < 16; ++u) ss = fmaf(y[u], y[u], ss);
    red[g][l] = ss;
    __syncthreads();
    float tot = red[0][l] + red[1][l] + red[2][l] + red[3][l];
    float inv = 1.0f / fmaxf(sqrtf(tot), 1e-12f);

    // Emit bf16 hi/lo split in fragment-tiled layout.
    // Channels c = g*16+u: chunk = g>>1; u<8 -> quad = (g&1)*2, j=u;
    // u>=8 -> quad = (g&1)*2+1, j=u-8.
    unsigned short hs[16], ls[16];
    #pragma unroll
    for (int u = 0; u < 16; ++u) {
        float val = y[u] * inv;
        hs[u] = f2bf(val);
        ls[u] = f2bf(val - bf2f(hs[u]));
    }
    {
        int col   = l0 + l;
        int tile  = col >> 4;
        int lnn   = col & 15;
        int chunk = g >> 1;
        int quad0 = (g & 1) * 2;
        size_t base0 = (((size_t)b * 256 + tile) * 2 + chunk) * 512
                     + (size_t)(quad0 * 16 + lnn) * 8;
        size_t base1 = base0 + 128;   // quad0+1 -> lane+16 -> +128 ushorts
        *(us8*)(dh + base0) = *(us8*)&hs[0];
        *(us8*)(dh + base1) = *(us8*)&hs[8];
        *(us8*)(dl + base0) = *(us8*)&ls[0];
        *(us8*)(dl + base1) = *(us8*)&ls[8];
    }
}

// ---------------------------------------------------------------------------
// Merged scores kernel: MFMA bf16x3, softmax(fixed shift 10), threshold.
// 512 blocks (b major) x 512 threads (8 waves); 32 q-rows per block.
// S = Qh*Kh + Qh*Kl + Ql*Kh (lo*lo dropped, ~4e-5 logit error). |S|<=10 so
// the softmax shift is the constant 10 (exp(S-10) in [2e-9,1], no max pass).
// ALL operand loads are fragment-tiled: base + lane*16B, fully contiguous
// 1 KB per wave instruction (see layout comment above).
// Pass 2 keeps the R10-verified instruction-contiguous cooperative store.
// ---------------------------------------------------------------------------
__global__ void __launch_bounds__(512) scores_kernel(
    const unsigned short* __restrict__ Qh, const unsigned short* __restrict__ Ql,
    const unsigned short* __restrict__ Kh, const unsigned short* __restrict__ Kl,
    float* __restrict__ out)
{
    int bid  = blockIdx.x;          // 0..511
    int b    = bid >> 7;
    int r0   = (bid & 127) << 5;    // 32 rows
    int t    = threadIdx.x;
    int wave = t >> 6;
    int lane = t & 63;
    int quad = lane >> 4;
    int ln   = lane & 15;

    // A fragments (fragment-tiled): aQ[rt][c0][hi/lo]
    bf16x8 aQ[2][2][2];
    {
        #pragma unroll
        for (int rt = 0; rt < 2; ++rt) {
            size_t rowtile = (size_t)b * 256 + (r0 >> 4) + rt;
            #pragma unroll
            for (int c0 = 0; c0 < 2; ++c0) {
                size_t base = (rowtile * 2 + c0) * 512 + (size_t)lane * 8;
                aQ[rt][c0][0] = *(const bf16x8*)(Qh + base);
                aQ[rt][c0][1] = *(const bf16x8*)(Ql + base);
            }
        }
    }

    const size_t ktb = (size_t)b * 256;
    __shared__ float wsum[32][8];
    __shared__ float rinv[32];
    __shared__ float Pt[2][32][132];   // double-buffered transpose tile

    // ---------------- pass 1: row sums of exp(S - 10) ----------------
    v4f ps[2];
    ps[0] = (v4f){0.f, 0.f, 0.f, 0.f};
    ps[1] = (v4f){0.f, 0.f, 0.f, 0.f};

    #pragma unroll 1
    for (int ct = 0; ct < 32; ++ct) {
        size_t base = ((ktb + wave * 32 + ct) * 2) * 512 + (size_t)lane * 8;
        bf16x8 bh0 = *(const bf16x8*)(Kh + base);
        bf16x8 bl0 = *(const bf16x8*)(Kl + base);
        bf16x8 bh1 = *(const bf16x8*)(Kh + base + 512);
        bf16x8 bl1 = *(const bf16x8*)(Kl + base + 512);

        #pragma unroll
        for (int rt = 0; rt < 2; ++rt) {
            v4f acc = (v4f){0.f, 0.f, 0.f, 0.f};
            acc = mfma16(aQ[rt][0][0], bh0, acc);
            acc = mfma16(aQ[rt][0][1], bh0, acc);
            acc = mfma16(aQ[rt][0][0], bl0, acc);
            acc = mfma16(aQ[rt][1][0], bh1, acc);
            acc = mfma16(aQ[rt][1][1], bh1, acc);
            acc = mfma16(aQ[rt][1][0], bl1, acc);
            #pragma unroll
            for (int r = 0; r < 4; ++r)
                ps[rt][r] += __expf(fmaf(SCALE, acc[r], -SCALE));
        }
    }

    // reduce over the 16 ln-lanes (cols) per row, then across waves via LDS
    #pragma unroll
    for (int rt = 0; rt < 2; ++rt) {
        #pragma unroll
        for (int r = 0; r < 4; ++r) {
            float s = ps[rt][r];
            s += __shfl_xor(s, 1);
            s += __shfl_xor(s, 2);
            s += __shfl_xor(s, 4);
            s += __shfl_xor(s, 8);
            if (ln == 0) wsum[rt * 16 + quad * 4 + r][wave] = s;
        }
    }
    __syncthreads();
    if (t < 32) {
        float s = 0.f;
        #pragma unroll
        for (int w = 0; w < 8; ++w) s += wsum[t][w];
        rinv[t] = 1.0f / s;
    }
    __syncthreads();

    float rv[2][4];
    #pragma unroll
    for (int rt = 0; rt < 2; ++rt)
        #pragma unroll
        for (int r = 0; r < 4; ++r)
            rv[rt][r] = rinv[rt * 16 + quad * 4 + r];

    // ---------------- pass 2: recompute, normalize, threshold, store ------
    float* __restrict__ outb = out + ((size_t)b * L + r0) * L;
    int srow = t >> 5;            // 0..15 (store row within half-tile)
    int scol = (t & 31) * 4;      // 0..124 (16 B-aligned col)

    #pragma unroll 1
    for (int T = 0; T < 32; ++T) {
        int buf = T & 1;
        size_t base = ((ktb + T * 8 + wave) * 2) * 512 + (size_t)lane * 8;
        bf16x8 bh0 = *(const bf16x8*)(Kh + base);
        bf16x8 bl0 = *(const bf16x8*)(Kl + base);
        bf16x8 bh1 = *(const bf16x8*)(Kh + base + 512);
        bf16x8 bl1 = *(const bf16x8*)(Kl + base + 512);

        #pragma unroll
        for (int rt = 0; rt < 2; ++rt) {
            v4f acc = (v4f){0.f, 0.f, 0.f, 0.f};
            acc = mfma16(aQ[rt][0][0], bh0, acc);
            acc = mfma16(aQ[rt][0][1], bh0, acc);
            acc = mfma16(aQ[rt][0][0], bl0, acc);
            acc = mfma16(aQ[rt][1][0], bh1, acc);
            acc = mfma16(aQ[rt][1][1], bh1, acc);
            acc = mfma16(aQ[rt][1][0], bl1, acc);
            #pragma unroll
            for (int r = 0; r < 4; ++r) {
                float w = __expf(fmaf(SCALE, acc[r], -SCALE)) * rv[rt][r];
                w = (w > THRESH) ? w : 0.f;
                // C/D layout: col = ln, row = quad*4 + r (m89/m91)
                Pt[buf][rt * 16 + quad * 4 + r][wave * 16 + ln] = w;
            }
        }
        __syncthreads();

        // instruction-level line-complete cooperative store:
        // each instruction = 64 lanes x 16 B fully contiguous (1 KiB).
        #pragma unroll
        for (int j = 0; j < 2; ++j) {
            int row = j * 16 + srow;
            v4f o = *(const v4f*)&Pt[buf][row][scol];
            *(v4f*)(outb + (size_t)row * L + T * 128 + scol) = o;
        }
    }
}

// ---------------------------------------------------------------------------
extern "C" void kernel_launch(void* const* d_in, const int* in_sizes, int n_in,
                              void* d_out, int out_size, void* d_ws, size_t ws_size,
                              hipStream_t stream) {
    const float* query = (const float*)d_in[0];
    const float* key   = (const float*)d_in[1];
    const float* W1    = (const float*)d_in[2];
    const float* W2    = (const float*)d_in[3];
    float* out = (float*)d_out;

    // ws layout (ushorts): Qh | Ql | Kh | Kl, each B*L*OUTC = 1048576 elems
    unsigned short* Qh = (unsigned short*)d_ws;
    unsigned short* Ql = Qh + (size_t)B * L * OUTC;
    unsigned short* Kh = Ql + (size_t)B * L * OUTC;
    unsigned short* Kl = Kh + (size_t)B * L * OUTC;

    hipLaunchKernelGGL(proj_kernel, dim3(512), dim3(256), 0, stream,
                       query, key, W1, W2, Qh, Ql, Kh, Kl);
    hipLaunchKernelGGL(scores_kernel, dim3(512), dim3(512), 0, stream,
                       Qh, Ql, Kh, Kl, out);
}